// Round 6
// baseline (147.645 us; speedup 1.0000x reference)
//
#include <hip/hip_runtime.h>

// out = 2 * heatmap_loss (offset term cancels: o / stopgrad(o/h) == h).
// heatmap_loss = sum_all(w * huber(pred,gt)) / 16  ->  out = sum/8.
//
// R6 probe: read via global_load_lds DMA (no VGPR return path) to test
// whether the ~3.3 TB/s read plateau is vector-load-path specific.

typedef float f4 __attribute__((ext_vector_type(4)));

__device__ __forceinline__ float hterm(float p, float g) {
    float err  = fabsf(p - g);
    float quad = fminf(err, 1.0f);      // clip(err, 0, delta=1)
    float lin  = err - quad;
    float h    = 0.5f * quad * quad + lin;
    float w    = (g != 0.0f) ? 1.5f : 0.6f;
    return w * h;
}

__device__ __forceinline__ float hterm4(f4 p, f4 g) {
    return hterm(p.x, g.x) + hterm(p.y, g.y) + hterm(p.z, g.z) + hterm(p.w, g.w);
}

#define CHUNK_F4 512     // f4s per input per iteration  (8 KB)
#define NITER    8       // per-block iterations
#define GRID     1024    // GRID * NITER * CHUNK_F4 = 4,194,304 = n4

__global__ __launch_bounds__(256) void heatmap_reduce_kernel(
        const f4* __restrict__ pred,
        const f4* __restrict__ gt,
        float* __restrict__ partial) {
    __shared__ f4 lds_pred[CHUNK_F4];   // 8 KB
    __shared__ f4 lds_gt[CHUNK_F4];     // 8 KB

    const int t    = threadIdx.x;
    const int wave = t >> 6;
    const int lane = t & 63;
    const int base = blockIdx.x * (CHUNK_F4 * NITER);   // f4 index

    float acc = 0.0f;
    for (int it = 0; it < NITER; ++it) {
        const int chunk = base + it * CHUNK_F4;
        // Stage 8 KB/input: 2 DMA insts per wave per input. LDS dst is
        // wave-uniform base; HW scatters at base + lane*16.
        #pragma unroll
        for (int k = 0; k < 2; ++k) {
            const int idx = wave * 128 + k * 64;   // f4 offset of this inst's 1 KB
            __builtin_amdgcn_global_load_lds(
                (const __attribute__((address_space(1))) void*)&pred[chunk + idx + lane],
                (__attribute__((address_space(3))) void*)&lds_pred[idx],
                16, 0, 0);
            __builtin_amdgcn_global_load_lds(
                (const __attribute__((address_space(1))) void*)&gt[chunk + idx + lane],
                (__attribute__((address_space(3))) void*)&lds_gt[idx],
                16, 0, 0);
        }
        __syncthreads();               // drains vmcnt, publishes LDS
        #pragma unroll
        for (int k = 0; k < 2; ++k)
            acc += hterm4(lds_pred[t + k * 256], lds_gt[t + k * 256]);
        __syncthreads();               // protect LDS before next overwrite
    }

    #pragma unroll
    for (int off = 32; off > 0; off >>= 1)
        acc += __shfl_down(acc, off, 64);

    __shared__ float wsum[4];
    if (lane == 0) wsum[wave] = acc;
    __syncthreads();

    if (t == 0)
        partial[blockIdx.x] = wsum[0] + wsum[1] + wsum[2] + wsum[3];
}

__global__ __launch_bounds__(256) void finalize_kernel(
        const float* __restrict__ partial, float* __restrict__ out, int nblocks) {
    float s = 0.0f;
    for (int i = threadIdx.x; i < nblocks; i += 256)
        s += partial[i];

    #pragma unroll
    for (int off = 32; off > 0; off >>= 1)
        s += __shfl_down(s, off, 64);

    __shared__ float wsum[4];
    int lane = threadIdx.x & 63;
    int wave = threadIdx.x >> 6;
    if (lane == 0) wsum[wave] = s;
    __syncthreads();

    if (threadIdx.x == 0)
        out[0] = (wsum[0] + wsum[1] + wsum[2] + wsum[3]) * 0.125f;
}

extern "C" void kernel_launch(void* const* d_in, const int* in_sizes, int n_in,
                              void* d_out, int out_size, void* d_ws, size_t ws_size,
                              hipStream_t stream) {
    const float* pred = (const float*)d_in[0];
    const float* gt   = (const float*)d_in[1];
    float* out     = (float*)d_out;
    float* partial = (float*)d_ws;

    heatmap_reduce_kernel<<<GRID, 256, 0, stream>>>(
        (const f4*)pred, (const f4*)gt, partial);

    finalize_kernel<<<1, 256, 0, stream>>>(partial, out, GRID);
}